// Round 2
// baseline (253.125 us; speedup 1.0000x reference)
//
#include <hip/hip_runtime.h>

typedef __bf16 bf16x8 __attribute__((ext_vector_type(8)));
typedef float floatx4 __attribute__((ext_vector_type(4)));
typedef float floatx16 __attribute__((ext_vector_type(16)));
typedef unsigned int u32;

#define BB 4
#define CC 256
#define NN 4096

__device__ __forceinline__ unsigned short f2bf(float f) {
  union { float f; unsigned u; } v; v.f = f;
  unsigned r = v.u + 0x7fffu + ((v.u >> 16) & 1u);
  return (unsigned short)(r >> 16);
}

__device__ __forceinline__ void async16(const void* g, void* l) {
  __builtin_amdgcn_global_load_lds((const __attribute__((address_space(1))) u32*)g,
                                   (__attribute__((address_space(3))) u32*)l, 16, 0, 0);
}

// ---------------- GroupNorm stats: 128 blocks, each reduces a contiguous 32768-float group ----
__global__ __launch_bounds__(256) void gn_stats(const float* __restrict__ x, float* __restrict__ mr) {
  int bg = blockIdx.x;
  const float* p = x + (size_t)bg * 32768;
  int t = threadIdx.x;
  float s = 0.f, q = 0.f;
#pragma unroll
  for (int it = 0; it < 32; ++it) {
    float4 v = *(const float4*)(p + it * 1024 + t * 4);
    s += v.x + v.y + v.z + v.w;
    q += v.x * v.x + v.y * v.y + v.z * v.z + v.w * v.w;
  }
#pragma unroll
  for (int off = 1; off < 64; off <<= 1) {
    s += __shfl_xor(s, off, 64);
    q += __shfl_xor(q, off, 64);
  }
  __shared__ float red[8];
  int w = t >> 6;
  if ((t & 63) == 0) { red[w] = s; red[4 + w] = q; }
  __syncthreads();
  if (t == 0) {
    float S = red[0] + red[1] + red[2] + red[3];
    float Q = red[4] + red[5] + red[6] + red[7];
    float mean = S * (1.f / 32768.f);
    float var = Q * (1.f / 32768.f) - mean * mean;
    mr[bg] = mean;
    mr[128 + bg] = rsqrtf(var + 1e-5f);
  }
}

// ---------------- normalize + transpose to normed[b][n][c] bf16 ----------------
__global__ __launch_bounds__(256) void gn_apply(const float* __restrict__ x, const float* __restrict__ mr,
                                                const float* __restrict__ gamma, const float* __restrict__ beta,
                                                unsigned short* __restrict__ normed) {
  int bid = blockIdx.x;              // b * 4(ctile) * 64(ntile)
  int nt = bid & 63;
  int ct = (bid >> 6) & 3;
  int b = bid >> 8;
  int c0 = ct * 64, n0 = nt * 64;
  __shared__ unsigned short T[64][80];   // [n][c], padded
  int t = threadIdx.x;
#pragma unroll
  for (int it = 0; it < 4; ++it) {
    int idx = it * 256 + t;
    int cl = idx >> 4;
    int n4 = (idx & 15) * 4;
    int c = c0 + cl;
    int bg = b * 32 + (c >> 3);
    float mean = mr[bg], rstd = mr[128 + bg];
    float sc = rstd * gamma[c];
    float sh = beta[c] - mean * sc;
    float4 v = *(const float4*)(x + ((size_t)(b * CC + c)) * NN + n0 + n4);
    T[n4 + 0][cl] = f2bf(v.x * sc + sh);
    T[n4 + 1][cl] = f2bf(v.y * sc + sh);
    T[n4 + 2][cl] = f2bf(v.z * sc + sh);
    T[n4 + 3][cl] = f2bf(v.w * sc + sh);
  }
  __syncthreads();
#pragma unroll
  for (int it = 0; it < 2; ++it) {
    int idx = it * 256 + t;
    int nl = idx >> 3, ck = idx & 7;
    uint4 val;
    unsigned short* pv = (unsigned short*)&val;
#pragma unroll
    for (int j = 0; j < 8; ++j) pv[j] = T[nl][ck * 8 + j];
    *(uint4*)(normed + ((size_t)b * NN + n0 + nl) * CC + c0 + ck * 8) = val;
  }
}

// ---------------- weight fp32 -> bf16 (q rows pre-scaled by log2(e)/sqrt(C)) ----------------
__global__ __launch_bounds__(256) void wconv(const float* __restrict__ wqkv, const float* __restrict__ wproj,
                                             unsigned short* __restrict__ wq_bf, unsigned short* __restrict__ wp_bf) {
  int i = blockIdx.x * 256 + threadIdx.x;      // 1024 blocks -> 262144
  if (i < 196608) {
    float v = wqkv[i];
    if (i < 65536) v *= 0.090168440055560213f;  // log2(e)/16
    wq_bf[i] = f2bf(v);
  } else {
    int j = i - 196608;
    wp_bf[j] = f2bf(wproj[j]);
  }
}

// ---------------- B^T GEMM: C[M][Nc] = A[M][256] * B[Nc][256]^T  (128x128 tiles) ----------------
template <int RESID>
__global__ __launch_bounds__(256) void gemm_bt(const unsigned short* __restrict__ A,
                                               const unsigned short* __restrict__ Bm,
                                               void* __restrict__ Cout, const float* __restrict__ resid,
                                               int mtiles, int ldc,
                                               long sA, long sB, long sC, long sR) {
  int mt = blockIdx.x % mtiles;
  int nt = blockIdx.x / mtiles;
  int b = blockIdx.y;
  int m0 = mt * 128, n0 = nt * 128;
  __shared__ unsigned short As[128][72];
  __shared__ unsigned short Bs[128][72];
  int t = threadIdx.x;
  int w = t >> 6, lane = t & 63;
  int l16 = lane & 15, quad = lane >> 4;
  int wr = w >> 1, wc = w & 1;
  const unsigned short* Ab = A + (size_t)b * sA + (size_t)m0 * 256;
  const unsigned short* Bb = Bm + (size_t)b * sB + (size_t)n0 * 256;
  floatx4 acc[4][4];
#pragma unroll
  for (int m = 0; m < 4; ++m)
#pragma unroll
    for (int n = 0; n < 4; ++n)
#pragma unroll
      for (int r = 0; r < 4; ++r) acc[m][n][r] = 0.f;

  for (int kb = 0; kb < 4; ++kb) {
    __syncthreads();
#pragma unroll
    for (int i = 0; i < 4; ++i) {
      int idx = i * 256 + t;
      int r = idx >> 3, ck = idx & 7;
      *(uint4*)&As[r][ck * 8] = *(const uint4*)(Ab + (size_t)r * 256 + kb * 64 + ck * 8);
      *(uint4*)&Bs[r][ck * 8] = *(const uint4*)(Bb + (size_t)r * 256 + kb * 64 + ck * 8);
    }
    __syncthreads();
#pragma unroll
    for (int kk = 0; kk < 2; ++kk) {
      bf16x8 af[4], bfr[4];
#pragma unroll
      for (int m = 0; m < 4; ++m) af[m] = *(const bf16x8*)&As[wr * 64 + m * 16 + l16][kk * 32 + quad * 8];
#pragma unroll
      for (int n = 0; n < 4; ++n) bfr[n] = *(const bf16x8*)&Bs[wc * 64 + n * 16 + l16][kk * 32 + quad * 8];
#pragma unroll
      for (int m = 0; m < 4; ++m)
#pragma unroll
        for (int n = 0; n < 4; ++n)
          acc[m][n] = __builtin_amdgcn_mfma_f32_16x16x32_bf16(af[m], bfr[n], acc[m][n], 0, 0, 0);
    }
  }
  size_t cb = (size_t)b * sC;
  size_t rb = (size_t)b * sR;
#pragma unroll
  for (int m = 0; m < 4; ++m)
#pragma unroll
    for (int n = 0; n < 4; ++n)
#pragma unroll
      for (int r = 0; r < 4; ++r) {
        int row = m0 + wr * 64 + m * 16 + quad * 4 + r;
        int col = n0 + wc * 64 + n * 16 + l16;
        size_t idx = (size_t)row * ldc + col;
        if (RESID)
          ((float*)Cout)[cb + idx] = acc[m][n][r] + resid[rb + idx];
        else
          ((unsigned short*)Cout)[cb + idx] = f2bf(acc[m][n][r]);
      }
}

// ---------------- fused attention v2: DMA double-buffered K/V, S^T trick, 1 barrier/iter ------
// Br=64, Bc=64, 4 waves: wave (wr = j-half, wc = i-half). Each wave:
//   S^T(32x32) = K(A-frag, LDS) . Q^T(B-frag, regs)  -> lane = column i, regs = rows j
//   P = exp2(S^T) in-register -> A-frag for PV via one hi-half shfl exchange
//   O_partial(i in wc-half, all 256 c) accumulated over own j-half; combined at end via LDS.
__global__ __launch_bounds__(256, 1) void attn(const unsigned short* __restrict__ qk,   // [B][N][512] (q|k)
                                               const unsigned short* __restrict__ vbuf, // [B][C][N]
                                               unsigned short* __restrict__ obuf) {     // [B][N][C]
  __shared__ char smem[132096];      // K: 2 x 32 pairs x 1040B = 66560 ; V: 2 x 32768 = 65536
  __shared__ float Lred[2][2][32];
  __shared__ float Linv[64];

  int xcd = blockIdx.x & 7, slot = blockIdx.x >> 3;
  int b = xcd >> 1;
  int qt = slot * 2 + (xcd & 1);
  int i0 = qt * 64;

  int t = threadIdx.x, w = t >> 6, l = t & 63;
  int l31 = l & 31, hi = l >> 5;
  int wr = w >> 1, wc = w & 1;

  const size_t bqk = (size_t)b * NN * 512;
  const size_t bv = (size_t)b * CC * NN;

  unsigned short* Kls = (unsigned short*)smem;             // elem stride per pair: 520
  unsigned short* Vls = (unsigned short*)(smem + 66560);

  // stage(tile, buf): async-DMA K-tile (64x256, row-pair blocks, stride 1040B)
  //                   and V-tile (256x64, 8c-row blocks, 16B-chunk XOR swizzle)
  auto stage = [&](int tile, int buf) {
    size_t kg = bqk + (size_t)tile * 64 * 512 + 256 + (size_t)hi * 512 + (size_t)l31 * 8;
    char* kb = smem + buf * 33280;
#pragma unroll
    for (int it = 0; it < 8; ++it) {
      int p = it * 4 + w;
      async16(qk + kg + (size_t)p * 1024, kb + p * 1040);
    }
    size_t vg = bv + (size_t)(l >> 3) * NN + (size_t)tile * 64 + (size_t)(((l & 7) ^ (l >> 3)) * 8);
    char* vb = smem + 66560 + buf * 32768;
#pragma unroll
    for (int it = 0; it < 8; ++it) {
      int q = it * 4 + w;
      async16(vbuf + vg + (size_t)q * 8 * NN, vb + q * 1024);
    }
  };

  stage(0, 0);

  // Q fragments (B-operand): lane = i = wc*32+l31, elems = c = ks*16 + hi*8 + 0..7
  bf16x8 qreg[16];
  {
    const unsigned short* qp = qk + bqk + (size_t)(i0 + wc * 32 + l31) * 512 + hi * 8;
#pragma unroll
    for (int ks = 0; ks < 16; ++ks)
      qreg[ks] = *(const bf16x8*)(qp + ks * 16);
  }

  // per-lane constant LDS offsets (elements)
  const int kbase = (wr * 16 + (l31 >> 1)) * 520 + (l31 & 1) * 256 + hi * 8;
  const int c7 = l31 & 7;
  const int jx0 = ((wr * 4 + 0 + hi) ^ c7) * 8;   // k-step 0 chunk
  const int jx1 = ((wr * 4 + 2 + hi) ^ c7) * 8;   // k-step 1 chunk

  floatx16 oacc[8];
#pragma unroll
  for (int cf = 0; cf < 8; ++cf)
#pragma unroll
    for (int r = 0; r < 16; ++r) oacc[cf][r] = 0.f;
  float lacc = 0.f;

  for (int kt = 0; kt < 64; ++kt) {
    int cur = kt & 1;
    __syncthreads();                       // tile kt DMA complete; everyone done with buf[1-cur]
    if (kt < 63) stage(kt + 1, cur ^ 1);   // prefetch in flight during compute

    const unsigned short* Kc = Kls + cur * 16640;
    const unsigned short* Vc = Vls + cur * 16384;

    // S^T = K . Q^T
    floatx16 st;
#pragma unroll
    for (int r = 0; r < 16; ++r) st[r] = 0.f;
#pragma unroll
    for (int ks = 0; ks < 16; ++ks) {
      bf16x8 kf = *(const bf16x8*)(Kc + kbase + ks * 16);
      st = __builtin_amdgcn_mfma_f32_32x32x16_bf16(kf, qreg[ks], st, 0, 0, 0);
    }

    // P = exp2(S^T), pack bf16 pairs along j
    u32 pr[8];
#pragma unroll
    for (int k2 = 0; k2 < 8; ++k2) {
      float p0 = __builtin_amdgcn_exp2f(st[2 * k2]);
      float p1 = __builtin_amdgcn_exp2f(st[2 * k2 + 1]);
      lacc += p0 + p1;
      pr[k2] = (u32)f2bf(p0) | ((u32)f2bf(p1) << 16);
    }

    // rearrange into PV A-fragments (j = wr*32 + s*16 + hi*8 + 0..7) via hi-half exchange
    union U { u32 u[4]; bf16x8 v; } a0, a1;
    {
      u32 sA = hi ? pr[0] : pr[2], sB = hi ? pr[1] : pr[3];
      u32 rA = (u32)__shfl_xor((int)sA, 32, 64);
      u32 rB = (u32)__shfl_xor((int)sB, 32, 64);
      a0.u[0] = hi ? rA : pr[0]; a0.u[1] = hi ? rB : pr[1];
      a0.u[2] = hi ? pr[2] : rA; a0.u[3] = hi ? pr[3] : rB;
      sA = hi ? pr[4] : pr[6]; sB = hi ? pr[5] : pr[7];
      rA = (u32)__shfl_xor((int)sA, 32, 64);
      rB = (u32)__shfl_xor((int)sB, 32, 64);
      a1.u[0] = hi ? rA : pr[4]; a1.u[1] = hi ? rB : pr[5];
      a1.u[2] = hi ? pr[6] : rA; a1.u[3] = hi ? pr[7] : rB;
    }

    // O_partial += P . V  (B-frag: lane = c = cf*32+l31, elems = j)
#pragma unroll
    for (int cf = 0; cf < 8; ++cf) {
      int vbcf = (cf * 4 + (l31 >> 3)) * 512 + c7 * 64;
      bf16x8 v0 = *(const bf16x8*)(Vc + vbcf + jx0);
      oacc[cf] = __builtin_amdgcn_mfma_f32_32x32x16_bf16(a0.v, v0, oacc[cf], 0, 0, 0);
      bf16x8 v1 = *(const bf16x8*)(Vc + vbcf + jx1);
      oacc[cf] = __builtin_amdgcn_mfma_f32_32x32x16_bf16(a1.v, v1, oacc[cf], 0, 0, 0);
    }
  }

  // ---- epilogue: l reduce, O partial combine (reuse K LDS region), scaled bf16 store ----
  float l2 = lacc + __shfl_xor(lacc, 32, 64);
  __syncthreads();
  if (hi == 0) Lred[wr][wc][l31] = l2;
  float* Of = (float*)smem;                 // [wc][i_local 32][c 256] floats = 64 KB
  if (wr == 1) {
#pragma unroll
    for (int cf = 0; cf < 8; ++cf)
#pragma unroll
      for (int r = 0; r < 16; ++r) {
        int il = (r & 3) + 8 * (r >> 2) + 4 * hi;
        Of[wc * 8192 + il * 256 + cf * 32 + l31] = oacc[cf][r];
      }
  }
  __syncthreads();
  if (t < 64) Linv[t] = 1.f / (Lred[0][t >> 5][t & 31] + Lred[1][t >> 5][t & 31]);
  if (wr == 0) {
#pragma unroll
    for (int cf = 0; cf < 8; ++cf)
#pragma unroll
      for (int r = 0; r < 16; ++r) {
        int il = (r & 3) + 8 * (r >> 2) + 4 * hi;
        Of[wc * 8192 + il * 256 + cf * 32 + l31] += oacc[cf][r];
      }
  }
  __syncthreads();
#pragma unroll
  for (int it = 0; it < 8; ++it) {
    int chunk = it * 256 + t;          // 2048 chunks of 8 elems
    int i = chunk >> 5;
    int cc = (chunk & 31) * 8;
    int base = (i >> 5) * 8192 + (i & 31) * 256 + cc;
    floatx4 v0 = *(const floatx4*)&Of[base];
    floatx4 v1 = *(const floatx4*)&Of[base + 4];
    float linv = Linv[i];
    union { unsigned short us[8]; uint4 q; } o;
#pragma unroll
    for (int j = 0; j < 4; ++j) {
      o.us[j] = f2bf(v0[j] * linv);
      o.us[4 + j] = f2bf(v1[j] * linv);
    }
    *(uint4*)(obuf + ((size_t)b * NN + i0 + i) * CC + cc) = o.q;
  }
}

extern "C" void kernel_launch(void* const* d_in, const int* in_sizes, int n_in,
                              void* d_out, int out_size, void* d_ws, size_t ws_size,
                              hipStream_t stream) {
  const float* x     = (const float*)d_in[0];
  // d_in[1] = t (unused)
  const float* gamma = (const float*)d_in[2];
  const float* beta  = (const float*)d_in[3];
  const float* wqkv  = (const float*)d_in[4];
  const float* wproj = (const float*)d_in[5];
  float* out = (float*)d_out;

  char* p = (char*)d_ws;
  float* mr               = (float*)(p + 0);          //  1 KB  mean[128] | rstd[128]
  unsigned short* wq_bf   = (unsigned short*)(p + 1024);       // 384 KB
  unsigned short* wp_bf   = (unsigned short*)(p + 394240);     // 128 KB
  unsigned short* normed  = (unsigned short*)(p + 525312);     // 8 MB  [b][n][c]
  unsigned short* qkbuf   = (unsigned short*)(p + 8913920);    // 16 MB [b][n][512]
  unsigned short* vbuf    = (unsigned short*)(p + 25691136);   // 8 MB  [b][c][n]
  unsigned short* obuf    = (unsigned short*)(p + 34079744);   // 8 MB  [b][n][c]
  unsigned short* wv_bf   = wq_bf + 512 * 256;

  wconv<<<1024, 256, 0, stream>>>(wqkv, wproj, wq_bf, wp_bf);
  gn_stats<<<128, 256, 0, stream>>>(x, mr);
  gn_apply<<<1024, 256, 0, stream>>>(x, mr, gamma, beta, normed);
  // qk[b][n][o] = normed[b][n][:] . wqkv[o][:]  (o<512)
  gemm_bt<0><<<dim3(128, 4), 256, 0, stream>>>(normed, wq_bf, qkbuf, nullptr,
                                               32, 512, (long)NN * CC, 0L, (long)NN * 512, 0L);
  // v[b][c][n] = wv[c][:] . normed[b][n][:]
  gemm_bt<0><<<dim3(64, 4), 256, 0, stream>>>(wv_bf, normed, vbuf, nullptr,
                                              2, 4096, 0L, (long)NN * CC, (long)CC * NN, 0L);
  attn<<<256, 256, 0, stream>>>(qkbuf, vbuf, obuf);
  // out[b][co][n] = wproj[co][:] . obuf[b][n][:] + x[b][co][n]
  gemm_bt<1><<<dim3(64, 4), 256, 0, stream>>>(wp_bf, obuf, out, x,
                                              2, 4096, 0L, (long)NN * CC, (long)CC * NN, (long)CC * NN);
}